// Round 7
// baseline (405.736 us; speedup 1.0000x reference)
//
#include <hip/hip_runtime.h>
#include <stdint.h>

// SingleStreamBlock on MI355X. fp32 in/out (per reference), bf16 MFMA compute.
// B=2 L=2048 HID=1024 NH=16 HD=64 MLP=4096.

#define HID  1024
#define NH   16
#define HD   64
#define MLP  4096
#define D1   7168   // 3*HID + MLP
#define DQKV 3072
#define DCAT 2048
#define BB   2
#define LL   2048
#define TOK  4096

typedef __attribute__((ext_vector_type(8))) short    bf16x8;
typedef __attribute__((ext_vector_type(4))) float    f32x4;
typedef __attribute__((ext_vector_type(4))) unsigned int u32x4;

__device__ __forceinline__ float b2f(unsigned short u) {
    unsigned int v = ((unsigned int)u) << 16;
    float f; __builtin_memcpy(&f, &v, 4); return f;
}
__device__ __forceinline__ unsigned short f2b(float f) {   // RNE
    unsigned int v; __builtin_memcpy(&v, &f, 4);
    unsigned int r = (v + 0x7FFFu + ((v >> 16) & 1u)) >> 16;
    return (unsigned short)r;
}
// cheap round-to-nearest pack of 2 floats -> 2 bf16 in a u32
__device__ __forceinline__ unsigned int pkbf2(float a, float b) {
    unsigned int ua, ub;
    __builtin_memcpy(&ua, &a, 4); __builtin_memcpy(&ub, &b, 4);
    return ((ua + 0x8000u) >> 16) | ((ub + 0x8000u) & 0xFFFF0000u);
}
// single-instruction pack of 2 f32 -> 2 bf16 (RNE), T12 recipe (no builtin)
__device__ __forceinline__ unsigned int cvtpk(float a, float b) {
    unsigned int r;
    asm("v_cvt_pk_bf16_f32 %0, %1, %2" : "=v"(r) : "v"(a), "v"(b));
    return r;
}
// async global->LDS, 16 B per lane (dest is wave-uniform base + lane*16)
__device__ __forceinline__ void gl_lds16(const unsigned short* g, unsigned short* l) {
    __builtin_amdgcn_global_load_lds(
        (const __attribute__((address_space(1))) unsigned int*)(g),
        (__attribute__((address_space(3))) unsigned int*)(l), 16, 0, 0);
}

// ---------------- merged transpose+cast: fp32 (R x C) -> bf16 (C x R) ----------------
// One dispatch for all 3 weights (w1, w_mlp, w2): removes launch gaps, overlaps tails.
__global__ void k_transpose3(const float* __restrict__ w1, unsigned short* __restrict__ w1T,
                             const float* __restrict__ wmlp, unsigned short* __restrict__ wmlpT,
                             const float* __restrict__ w2, unsigned short* __restrict__ w2T) {
    __shared__ float tile[32][33];
    int id = blockIdx.x;
    const float* in; unsigned short* out; int R, C, bx, by;
    if (id < 7168) {            // w1: R=1024 C=7168, grid (224,32)
        in = w1; out = w1T; R = 1024; C = 7168; bx = id % 224; by = id / 224;
    } else if (id < 11264) {    // w_mlp: R=4096 C=1024, grid (32,128)
        int j = id - 7168; in = wmlp; out = wmlpT; R = 4096; C = 1024; bx = j & 31; by = j >> 5;
    } else {                    // w2: R=2048 C=1024, grid (32,64)
        int j = id - 11264; in = w2; out = w2T; R = 2048; C = 1024; bx = j & 31; by = j >> 5;
    }
    int tx = threadIdx.x, ty = threadIdx.y;   // (32,8)
    #pragma unroll
    for (int i = 0; i < 4; i++) {
        int r = by * 32 + ty + i * 8;
        int c = bx * 32 + tx;
        tile[ty + i * 8][tx] = in[(size_t)r * C + c];
    }
    __syncthreads();
    #pragma unroll
    for (int i = 0; i < 4; i++) {
        int ro = bx * 32 + ty + i * 8;   // original col
        int co = by * 32 + tx;           // original row
        out[(size_t)ro * R + co] = f2b(tile[tx][ty + i * 8]);
    }
}

// ---------------- V transpose: h V-block -> vT[bh][d=64][l=2048] (bf16) ----------------
// Moves attn's per-tile V-transpose bit-twiddling (VALU-bound hot loop) into a
// one-shot memory-bound kernel. grid (LL/64, BB*NH), block 256.
__global__ void k_vtrans(const unsigned short* __restrict__ h,
                         unsigned short* __restrict__ vT) {
    __shared__ unsigned short tile[64][72];   // +8 pad, 144B rows (16B-aligned)
    int bh = blockIdx.y;
    int b = bh >> 4, hh = bh & 15;
    int l0 = blockIdx.x * 64;
    int t = threadIdx.x;
    int r = t >> 2, c8 = (t & 3) * 16;        // row 0..63, elem chunk
    const unsigned short* src = h + (size_t)b * LL * D1 + (size_t)(l0 + r) * D1
                                  + 2 * HID + hh * HD;
    u32x4 v0 = *(const u32x4*)(src + c8);
    u32x4 v1 = *(const u32x4*)(src + c8 + 8);
    *(u32x4*)(&tile[r][c8]) = v0;
    *(u32x4*)(&tile[r][c8 + 8]) = v1;
    __syncthreads();
    // write d-major: thread -> d row od, 16 keys
    int od = t >> 2, k0 = (t & 3) * 16;
    unsigned short* dst = vT + ((size_t)bh * 64 + od) * LL + l0 + k0;
    u32x4 o0, o1;
    #pragma unroll
    for (int j = 0; j < 4; j++) {
        o0[j] = (unsigned int)tile[k0 + 2*j][od] | ((unsigned int)tile[k0 + 2*j + 1][od] << 16);
        o1[j] = (unsigned int)tile[k0 + 8 + 2*j][od] | ((unsigned int)tile[k0 + 9 + 2*j][od] << 16);
    }
    *(u32x4*)(dst) = o0;
    *(u32x4*)(dst + 8) = o1;
}

// ---------------- mod = silu(vec) @ w_mod + b_mod (fp32) ----------------
__global__ void k_mod(const float* __restrict__ vec,
                      const float* __restrict__ w_mod,
                      const float* __restrict__ b_mod,
                      float* __restrict__ mod) {
    __shared__ float sv[HID];
    __shared__ float red[8][32];
    int b = blockIdx.y, t = threadIdx.x;
    for (int j = t; j < HID; j += 256) {
        float v = vec[b * HID + j];
        sv[j] = v / (1.0f + __expf(-v));
    }
    __syncthreads();
    int n0 = blockIdx.x * 32;
    int on = t & 31, ks = t >> 5;
    float acc = 0.f;
    const float* wp = w_mod + (size_t)(ks * 128) * 3072 + n0 + on;
    #pragma unroll 4
    for (int k = 0; k < 128; k++) acc += sv[ks * 128 + k] * wp[(size_t)k * 3072];
    red[ks][on] = acc;
    __syncthreads();
    if (t < 32) {
        float s = 0.f;
        #pragma unroll
        for (int i = 0; i < 8; i++) s += red[i][t];
        mod[b * 3072 + n0 + t] = s + b_mod[n0 + t];
    }
}

// ---------------- x_mod = (1+scale)*layernorm(x) + shift, bf16 out ----------------
__global__ void k_lnmod(const float* __restrict__ x,
                        const float* __restrict__ mod,
                        unsigned short* __restrict__ xmod) {
    int tok = blockIdx.x;
    int t = threadIdx.x;
    int b = tok >> 11;
    float4 v4 = *(const float4*)(x + (size_t)tok * HID + t * 4);
    float v0 = v4.x, v1 = v4.y, v2 = v4.z, v3 = v4.w;
    float s  = v0 + v1 + v2 + v3;
    float sq = v0*v0 + v1*v1 + v2*v2 + v3*v3;
    for (int off = 1; off < 64; off <<= 1) {
        s  += __shfl_xor(s,  off);
        sq += __shfl_xor(sq, off);
    }
    __shared__ float ls[4], lq[4];
    int w = t >> 6;
    if ((t & 63) == 0) { ls[w] = s; lq[w] = sq; }
    __syncthreads();
    s  = ls[0] + ls[1] + ls[2] + ls[3];
    sq = lq[0] + lq[1] + lq[2] + lq[3];
    float mean = s * (1.0f / HID);
    float var  = sq * (1.0f / HID) - mean * mean;
    float rstd = rsqrtf(var + 1e-6f);
    const float* mb = mod + b * 3072;
    float y[4] = {v0, v1, v2, v3};
    unsigned short r[4];
    #pragma unroll
    for (int j = 0; j < 4; j++) {
        int col = t * 4 + j;
        float nval = (y[j] - mean) * rstd;
        r[j] = f2b((1.0f + mb[1024 + col]) * nval + mb[col]);
    }
    unsigned int o0 = (unsigned int)r[0] | ((unsigned int)r[1] << 16);
    unsigned int o1 = (unsigned int)r[2] | ((unsigned int)r[3] << 16);
    *(uint2*)(xmod + (size_t)tok * HID + t * 4) = make_uint2(o0, o1);
}

// ---------------- MFMA GEMM (BK=64, global_load_lds staging, XOR-8 swizzle) ----------------
// C[M,N] = A[M,K](bf16) @ Bt[N,K](bf16)^T + bias(f32)
// EPI: 0 = store bf16; 3 = split-K fp32 partial (no bias), gridDim.z splits K
template<int EPI>
__global__ __launch_bounds__(256) void k_gemm(
    const unsigned short* __restrict__ A, int lda,
    const unsigned short* __restrict__ Bt, int ldb,
    const float* __restrict__ bias,
    unsigned short* __restrict__ C, float* __restrict__ Cf, int ldc,
    int K,
    const float* __restrict__ xin,
    const float* __restrict__ mod) {
    __shared__ alignas(16) unsigned short As[128 * 64];
    __shared__ alignas(16) unsigned short Bs[128 * 64];
    int t = threadIdx.x;
    int bm = blockIdx.x, bn = blockIdx.y;
    int lane = t & 63, wave = t >> 6;
    int wm = (wave >> 1) * 64, wn = (wave & 1) * 64;
    int ln = lane & 15, kq = lane >> 4;
    int ln7 = ln & 7;

    f32x4 acc[4][4];
    #pragma unroll
    for (int i = 0; i < 4; i++)
        #pragma unroll
        for (int j = 0; j < 4; j++) acc[i][j] = {0.f, 0.f, 0.f, 0.f};

    int sr  = t >> 3;
    int scg = (t & 7) ^ (sr & 7);
    const unsigned short* Ab = A  + (size_t)(bm * 128) * lda;
    const unsigned short* Bb = Bt + (size_t)(bn * 128) * ldb;

    int ksplit = K / gridDim.z;
    int kbeg = blockIdx.z * ksplit, kend = kbeg + ksplit;

    for (int k0 = kbeg; k0 < kend; k0 += 64) {
        __syncthreads();
        #pragma unroll
        for (int c = 0; c < 4; c++) {
            gl_lds16(Ab + (size_t)(c * 32 + sr) * lda + k0 + scg * 8, &As[c * 2048 + t * 8]);
            gl_lds16(Bb + (size_t)(c * 32 + sr) * ldb + k0 + scg * 8, &Bs[c * 2048 + t * 8]);
        }
        __syncthreads();
        #pragma unroll
        for (int ks = 0; ks < 2; ks++) {
            int slot = ((ks * 4 + kq) ^ ln7) * 8;
            bf16x8 af[4], bfr[4];
            #pragma unroll
            for (int i = 0; i < 4; i++)
                af[i] = *(const bf16x8*)(&As[(wm + i * 16 + ln) * 64 + slot]);
            #pragma unroll
            for (int j = 0; j < 4; j++)
                bfr[j] = *(const bf16x8*)(&Bs[(wn + j * 16 + ln) * 64 + slot]);
            #pragma unroll
            for (int i = 0; i < 4; i++)
                #pragma unroll
                for (int j = 0; j < 4; j++)
                    acc[i][j] = __builtin_amdgcn_mfma_f32_16x16x32_bf16(af[i], bfr[j], acc[i][j], 0, 0, 0);
        }
    }

    #pragma unroll
    for (int i = 0; i < 4; i++) {
        #pragma unroll
        for (int j = 0; j < 4; j++) {
            int col = bn * 128 + wn + j * 16 + ln;
            float bv = (EPI == 3) ? 0.f : bias[col];
            #pragma unroll
            for (int r = 0; r < 4; r++) {
                int row = bm * 128 + wm + i * 16 + kq * 4 + r;
                float v = acc[i][j][r] + bv;
                if (EPI == 0) {
                    C[(size_t)row * ldc + col] = f2b(v);
                } else if (EPI == 1) {
                    C[(size_t)row * ldc + col] = f2b(tanhf(v));
                } else if (EPI == 2) {
                    int b = row >> 11;
                    Cf[(size_t)row * ldc + col] =
                        xin[(size_t)row * HID + col] + mod[b * 3072 + 2048 + col] * v;
                } else {
                    Cf[((size_t)blockIdx.z * TOK + row) * ldc + col] = v;
                }
            }
        }
    }
}

// ---------------- split-K reduce 1: cat[:,1024:] = tanh(p0+p1+bias) ----------------
__global__ __launch_bounds__(256) void k_red1(const float* __restrict__ part,
                                              const float* __restrict__ bias,
                                              unsigned short* __restrict__ cat) {
    int idx = blockIdx.x * 256 + threadIdx.x;
    int row = idx >> 8;
    int c4  = (idx & 255) * 4;
    float4 p0 = *(const float4*)(part + (size_t)row * HID + c4);
    float4 p1 = *(const float4*)(part + ((size_t)TOK + row) * HID + c4);
    float4 bv = *(const float4*)(bias + c4);
    float a0 = tanhf(p0.x + p1.x + bv.x);
    float a1 = tanhf(p0.y + p1.y + bv.y);
    float a2 = tanhf(p0.z + p1.z + bv.z);
    float a3 = tanhf(p0.w + p1.w + bv.w);
    *(uint2*)(&cat[(size_t)row * DCAT + HID + c4]) =
        make_uint2(pkbf2(a0, a1), pkbf2(a2, a3));
}

// ---------------- split-K reduce 2: out = x + gate*(p0+p1+bias) (fp32) ----------------
__global__ __launch_bounds__(256) void k_red2(const float* __restrict__ part,
                                              const float* __restrict__ bias,
                                              const float* __restrict__ x,
                                              const float* __restrict__ mod,
                                              float* __restrict__ out) {
    int idx = blockIdx.x * 256 + threadIdx.x;
    int row = idx >> 8;
    int c4  = (idx & 255) * 4;
    int b = row >> 11;
    float4 p0 = *(const float4*)(part + (size_t)row * HID + c4);
    float4 p1 = *(const float4*)(part + ((size_t)TOK + row) * HID + c4);
    float4 bv = *(const float4*)(bias + c4);
    float4 gv = *(const float4*)(mod + b * 3072 + 2048 + c4);
    float4 xv = *(const float4*)(x + (size_t)row * HID + c4);
    float4 o;
    o.x = xv.x + gv.x * (p0.x + p1.x + bv.x);
    o.y = xv.y + gv.y * (p0.y + p1.y + bv.y);
    o.z = xv.z + gv.z * (p0.z + p1.z + bv.z);
    o.w = xv.w + gv.w * (p0.w + p1.w + bv.w);
    *(float4*)(out + (size_t)row * HID + c4) = o;
}

// ---------------- per-head RMSNorm + RoPE on q,k (in place in h, bf16) ----------------
// q additionally pre-scaled by 0.125*log2(e) so attention softmax runs in exp2 domain.
__global__ void k_qkrope(unsigned short* __restrict__ h,
                         const float* __restrict__ pe,
                         const float* __restrict__ q_scale,
                         const float* __restrict__ k_scale) {
    int tok = blockIdx.x;
    int l = tok & (LL - 1);
    int t = threadIdx.x;
    int lane = t & 63, wave = t >> 6;
    int hh = wave * 4 + (lane >> 4);      // head 0..15
    int d0 = (lane & 15) * 4;             // 4 dims = 2 rope pairs
    unsigned short* row = h + (size_t)tok * D1;
    int i0 = d0 >> 1;
    const float* peb = pe + ((size_t)l * 32 + i0) * 4;
    float4 e0 = *(const float4*)(peb);
    float4 e1 = *(const float4*)(peb + 4);
    #pragma unroll
    for (int qk = 0; qk < 2; qk++) {
        unsigned short* p = row + qk * HID + hh * HD + d0;
        const float* sc = (qk == 0 ? q_scale : k_scale) + d0;
        uint2 qv = *(const uint2*)p;
        float v0 = b2f((unsigned short)(qv.x & 0xFFFF)), v1 = b2f((unsigned short)(qv.x >> 16));
        float v2 = b2f((unsigned short)(qv.y & 0xFFFF)), v3 = b2f((unsigned short)(qv.y >> 16));
        float ssq = v0*v0 + v1*v1 + v2*v2 + v3*v3;
        ssq += __shfl_xor(ssq, 1, 16);
        ssq += __shfl_xor(ssq, 2, 16);
        ssq += __shfl_xor(ssq, 4, 16);
        ssq += __shfl_xor(ssq, 8, 16);
        float rr = rsqrtf(ssq * (1.0f / HD) + 1e-6f);
        if (qk == 0) rr *= 0.18033688011112042f;   // 0.125 * log2(e)
        v0 *= rr * sc[0];
        v1 *= rr * sc[1];
        v2 *= rr * sc[2];
        v3 *= rr * sc[3];
        float o0 = e0.x*v0 + e0.y*v1;
        float o1 = e0.z*v0 + e0.w*v1;
        float o2 = e1.x*v2 + e1.y*v3;
        float o3 = e1.z*v2 + e1.w*v3;
        *(uint2*)p = make_uint2(pkbf2(o0, o1), pkbf2(o2, o3));
    }
}

// ---------------- MFMA flash attention (exp2 domain, 64 Q-rows/block) ----------------
// LDS layout: [row][64] bf16, 128 B rows, XOR-chunk swizzle (T2).
// T14 async-stage: next K/V tile loaded to regs right after LDS writes.
// V comes pre-transposed (vT[bh][d][l]) so staging is 2 u32x4 copies like K.
#define KT 64            // keys per tile
__global__ __launch_bounds__(256) void k_attn(const unsigned short* __restrict__ h,
                                              const unsigned short* __restrict__ vT,
                                              unsigned short* __restrict__ cat) {
    __shared__ unsigned short Ks[KT * 64];         // [key][d]   swizzled
    __shared__ unsigned short Vt[HD * 64];         // [d][key]   swizzled
    __shared__ unsigned short Ps[4 * 16 * 64];     // per-wave [q][key] swizzled
    int t = threadIdx.x;
    int bx = blockIdx.x;               // Q tile 0..31 (64 rows)
    int bh = blockIdx.y;               // 0..31
    int b = bh >> 4, hh = bh & 15;
    int lane = t & 63, w = t >> 6;
    int ln = lane & 15, quad = lane >> 4;
    int ln7 = ln & 7;
    const unsigned short* hb = h + (size_t)b * LL * D1;

    int swk[2];
    swk[0] = ((0 + quad) ^ ln7) * 8;
    swk[1] = ((4 + quad) ^ ln7) * 8;

    bf16x8 qf[2];
    {
        const unsigned short* qbase = hb + (size_t)(bx * 64 + w * 16) * D1 + hh * HD;
        #pragma unroll
        for (int ks = 0; ks < 2; ks++)
            qf[ks] = *(const bf16x8*)(qbase + (size_t)ln * D1 + ks * 32 + quad * 8);
    }

    f32x4 O[4];
    #pragma unroll
    for (int vn = 0; vn < 4; vn++) O[vn] = {0.f, 0.f, 0.f, 0.f};
    float m_ = -1e30f, l_ = 0.f;

    unsigned short* Psw = Ps + w * 16 * 64;

    int skey = t >> 2, sdc16 = (t & 3) * 16, sc2 = (t & 3) * 2;
    const unsigned short* kbase0 = hb + HID + hh * HD;
    const unsigned short* vbase0 = vT + ((size_t)bh * 64 + skey) * LL;  // row = d

    // T14: preload tile 0 into registers (K rows strided; V rows contiguous from vT)
    u32x4 ka = *(const u32x4*)(kbase0 + (size_t)skey * D1 + sdc16);
    u32x4 kc = *(const u32x4*)(kbase0 + (size_t)skey * D1 + sdc16 + 8);
    u32x4 va = *(const u32x4*)(vbase0 + sdc16);
    u32x4 vb = *(const u32x4*)(vbase0 + sdc16 + 8);

    for (int kb = 0; kb < LL / KT; kb++) {
        __syncthreads();   // previous tile's LDS reads complete
        {   // write staged regs -> LDS, XOR-chunk swizzle (identical algebra K and V)
            int k7 = skey & 7;
            *(u32x4*)(&Ks[skey * 64 + ((sc2 ^ k7) * 8)]) = ka;
            *(u32x4*)(&Ks[skey * 64 + (((sc2 + 1) ^ k7) * 8)]) = kc;
            *(u32x4*)(&Vt[skey * 64 + ((sc2 ^ k7) * 8)]) = va;
            *(u32x4*)(&Vt[skey * 64 + (((sc2 + 1) ^ k7) * 8)]) = vb;
        }
        __syncthreads();
        if (kb + 1 < LL / KT) {   // T14: issue next-tile loads under compute
            const unsigned short* kb1 = kbase0 + (size_t)(kb + 1) * KT * D1;
            const unsigned short* vb1 = vbase0 + (size_t)(kb + 1) * KT;
            ka = *(const u32x4*)(kb1 + (size_t)skey * D1 + sdc16);
            kc = *(const u32x4*)(kb1 + (size_t)skey * D1 + sdc16 + 8);
            va = *(const u32x4*)(vb1 + sdc16);
            vb = *(const u32x4*)(vb1 + sdc16 + 8);
        }

        // S^T = K @ Q^T : D[row=key=kt*16+quad*4+r][col=q=ln]
        f32x4 st[4];
        __builtin_amdgcn_s_setprio(1);
        #pragma unroll
        for (int kt = 0; kt < 4; kt++) {
            st[kt] = {0.f, 0.f, 0.f, 0.f};
            #pragma unroll
            for (int ks = 0; ks < 2; ks++) {
                bf16x8 kf = *(const bf16x8*)(&Ks[(kt * 16 + ln) * 64 + swk[ks]]);
                st[kt] = __builtin_amdgcn_mfma_f32_16x16x32_bf16(kf, qf[ks], st[kt], 0, 0, 0);
            }
        }
        __builtin_amdgcn_s_setprio(0);

        // online softmax (exp2 domain, defer-max)
        {
            float p[16];
            #pragma unroll
            for (int kt = 0; kt < 4; kt++)
                #pragma unroll
                for (int r = 0; r < 4; r++) p[kt * 4 + r] = st[kt][r];
            float a0 = fmaxf(fmaxf(p[0],  p[1]),  p[2]);
            float a1 = fmaxf(fmaxf(p[3],  p[4]),  p[5]);
            float a2 = fmaxf(fmaxf(p[6],  p[7]),  p[8]);
            float a3 = fmaxf(fmaxf(p[9],  p[10]), p[11]);
            float a4 = fmaxf(fmaxf(p[12], p[13]), p[14]);
            float mx = fmaxf(fmaxf(fmaxf(a0, a1), a2), fmaxf(fmaxf(a3, a4), p[15]));
            mx = fmaxf(mx, __shfl_xor(mx, 16));
            mx = fmaxf(mx, __shfl_xor(mx, 32));
            if (!__all(mx - m_ <= 10.f)) {
                float mnew = fmaxf(m_, mx);
                float alpha = __builtin_amdgcn_exp2f(m_ - mnew);
                m_ = mnew;
                l_ *= alpha;
                #pragma unroll
                for (int vn = 0; vn < 4; vn++)
                    #pragma unroll
                    for (int r = 0; r < 4; r++) O[vn][r] *= alpha;
            }
            #pragma unroll
            for (int i = 0; i < 16; i++) p[i] = __builtin_amdgcn_exp2f(p[i] - m_);
            float s0 = (p[0] + p[1]) + (p[2] + p[3]);
            float s1 = (p[4] + p[5]) + (p[6] + p[7]);
            float s2 = (p[8] + p[9]) + (p[10] + p[11]);
            float s3 = (p[12] + p[13]) + (p[14] + p[15]);
            float sum = (s0 + s1) + (s2 + s3);
            sum += __shfl_xor(sum, 16);
            sum += __shfl_xor(sum, 32);
            l_ += sum;
            #pragma unroll
            for (int kt = 0; kt < 4; kt++) {
                unsigned int w0 = cvtpk(p[kt*4+0], p[kt*4+1]);
                unsigned int w1 = cvtpk(p[kt*4+2], p[kt*4+3]);
                int pchunk = (2 * kt + (quad >> 1)) ^ ln7;
                *(uint2*)(&Psw[ln * 64 + pchunk * 8 + (quad & 1) * 4]) = make_uint2(w0, w1);
            }
        }

        // O^T += V^T @ P^T
        __builtin_amdgcn_s_setprio(1);
        #pragma unroll
        for (int kt2 = 0; kt2 < 2; kt2++) {
            bf16x8 pb = *(const bf16x8*)(&Psw[ln * 64 + swk[kt2]]);
            #pragma unroll
            for (int vn = 0; vn < 4; vn++) {
                bf16x8 vf = *(const bf16x8*)(&Vt[(vn * 16 + ln) * 64 + swk[kt2]]);
                O[vn] = __builtin_amdgcn_mfma_f32_16x16x32_bf16(vf, pb, O[vn], 0, 0, 0);
            }
        }
        __builtin_amdgcn_s_setprio(0);
    }

    // epilogue: O^T[d][q] / l -> cat[token][hh*64+d]
    {
        float rl = 1.0f / l_;
        size_t row = (size_t)(b * LL + bx * 64 + w * 16 + ln);
        #pragma unroll
        for (int vn = 0; vn < 4; vn++) {
            #pragma unroll
            for (int r2 = 0; r2 < 4; r2 += 2) {
                unsigned int pk = cvtpk(O[vn][r2] * rl, O[vn][r2 + 1] * rl);
                *(unsigned int*)(&cat[row * DCAT + hh * HD + vn * 16 + quad * 4 + r2]) = pk;
            }
        }
    }
}

// ---------------- host launch ----------------
extern "C" void kernel_launch(void* const* d_in, const int* in_sizes, int n_in,
                              void* d_out, int out_size, void* d_ws, size_t ws_size,
                              hipStream_t stream) {
    const float* x       = (const float*)d_in[0];
    const float* vec     = (const float*)d_in[1];
    const float* pe      = (const float*)d_in[2];
    const float* w_mod   = (const float*)d_in[3];
    const float* b_mod   = (const float*)d_in[4];
    const float* w1      = (const float*)d_in[5];
    const float* b1      = (const float*)d_in[6];
    const float* w_mlp   = (const float*)d_in[7];
    const float* b_mlp   = (const float*)d_in[8];
    const float* w2      = (const float*)d_in[9];
    const float* b2      = (const float*)d_in[10];
    const float* q_scale = (const float*)d_in[11];
    const float* k_scale = (const float*)d_in[12];
    float* out = (float*)d_out;

    char* ws = (char*)d_ws;
    size_t off = 0;
    float* mod = (float*)(ws + off);                     off += 6144 * 4;
    unsigned short* xmod  = (unsigned short*)(ws + off); off += (size_t)TOK * HID * 2;
    unsigned short* h     = (unsigned short*)(ws + off); off += (size_t)TOK * D1 * 2;
    unsigned short* cat   = (unsigned short*)(ws + off); off += (size_t)TOK * DCAT * 2;
    unsigned short* w1T   = (unsigned short*)(ws + off); off += (size_t)D1 * HID * 2;
    unsigned short* wmlpT = (unsigned short*)(ws + off); off += (size_t)HID * MLP * 2;
    unsigned short* w2T   = (unsigned short*)(ws + off); off += (size_t)HID * DCAT * 2;
    float* part = (float*)(ws + off);                    off += (size_t)2 * TOK * HID * 4;
    unsigned short* vT    = (unsigned short*)(ws + off); off += (size_t)BB * NH * HD * LL * 2;

    // all 3 weight transposes in one dispatch
    k_transpose3<<<dim3(13312), dim3(32, 8), 0, stream>>>(w1, w1T, w_mlp, wmlpT, w2, w2T);

    k_mod<<<dim3(96, BB), 256, 0, stream>>>(vec, w_mod, b_mod, mod);
    k_lnmod<<<TOK, 256, 0, stream>>>(x, mod, xmod);

    // h = x_mod @ w1 + b1   (M=4096, N=7168, K=1024) — proven 128² kernel
    k_gemm<0><<<dim3(TOK / 128, D1 / 128), 256, 0, stream>>>(
        xmod, HID, w1T, HID, b1, h, nullptr, D1, HID, nullptr, nullptr);

    k_qkrope<<<TOK, 256, 0, stream>>>(h, pe, q_scale, k_scale);
    k_vtrans<<<dim3(LL / 64, BB * NH), 256, 0, stream>>>(h, vT);

    k_attn<<<dim3(LL / 64, BB * NH), 256, 0, stream>>>(h, vT, cat);

    // mlp partials: h_mlp @ w_mlp   (M=4096, N=1024, K=4096, split-K=2)
    k_gemm<3><<<dim3(TOK / 128, HID / 128, 2), 256, 0, stream>>>(
        h + DQKV, D1, wmlpT, MLP, b_mlp, nullptr, part, HID, MLP, nullptr, nullptr);
    k_red1<<<TOK * HID / 1024, 256, 0, stream>>>(part, b_mlp, cat);

    // out partials: cat @ w2   (M=4096, N=1024, K=2048, split-K=2)
    k_gemm<3><<<dim3(TOK / 128, HID / 128, 2), 256, 0, stream>>>(
        cat, DCAT, w2T, DCAT, b2, nullptr, part, HID, DCAT, nullptr, nullptr);
    k_red2<<<TOK * HID / 1024, 256, 0, stream>>>(part, b2, x, mod, out);
}

// Round 8
// 393.274 us; speedup vs baseline: 1.0317x; 1.0317x over previous
//
#include <hip/hip_runtime.h>
#include <stdint.h>

// SingleStreamBlock on MI355X. fp32 in/out (per reference), bf16 MFMA compute.
// B=2 L=2048 HID=1024 NH=16 HD=64 MLP=4096.

#define HID  1024
#define NH   16
#define HD   64
#define MLP  4096
#define D1   7168   // 3*HID + MLP
#define DQKV 3072
#define DCAT 2048
#define BB   2
#define LL   2048
#define TOK  4096

typedef __attribute__((ext_vector_type(8))) short    bf16x8;
typedef __attribute__((ext_vector_type(4))) float    f32x4;
typedef __attribute__((ext_vector_type(4))) unsigned int u32x4;

__device__ __forceinline__ float b2f(unsigned short u) {
    unsigned int v = ((unsigned int)u) << 16;
    float f; __builtin_memcpy(&f, &v, 4); return f;
}
__device__ __forceinline__ unsigned short f2b(float f) {   // RNE
    unsigned int v; __builtin_memcpy(&v, &f, 4);
    unsigned int r = (v + 0x7FFFu + ((v >> 16) & 1u)) >> 16;
    return (unsigned short)r;
}
// cheap round-to-nearest pack of 2 floats -> 2 bf16 in a u32
__device__ __forceinline__ unsigned int pkbf2(float a, float b) {
    unsigned int ua, ub;
    __builtin_memcpy(&ua, &a, 4); __builtin_memcpy(&ub, &b, 4);
    return ((ua + 0x8000u) >> 16) | ((ub + 0x8000u) & 0xFFFF0000u);
}
// single-instruction pack of 2 f32 -> 2 bf16 (RNE), T12 recipe (no builtin)
__device__ __forceinline__ unsigned int cvtpk(float a, float b) {
    unsigned int r;
    asm("v_cvt_pk_bf16_f32 %0, %1, %2" : "=v"(r) : "v"(a), "v"(b));
    return r;
}
// async global->LDS, 16 B per lane (dest is wave-uniform base + lane*16)
__device__ __forceinline__ void gl_lds16(const unsigned short* g, unsigned short* l) {
    __builtin_amdgcn_global_load_lds(
        (const __attribute__((address_space(1))) unsigned int*)(g),
        (__attribute__((address_space(3))) unsigned int*)(l), 16, 0, 0);
}

// ---------------- merged transpose+cast: fp32 (R x C) -> bf16 (C x R) ----------------
__global__ void k_transpose3(const float* __restrict__ w1, unsigned short* __restrict__ w1T,
                             const float* __restrict__ wmlp, unsigned short* __restrict__ wmlpT,
                             const float* __restrict__ w2, unsigned short* __restrict__ w2T) {
    __shared__ float tile[32][33];
    int id = blockIdx.x;
    const float* in; unsigned short* out; int R, C, bx, by;
    if (id < 7168) {            // w1: R=1024 C=7168
        in = w1; out = w1T; R = 1024; C = 7168; bx = id % 224; by = id / 224;
    } else if (id < 11264) {    // w_mlp: R=4096 C=1024
        int j = id - 7168; in = wmlp; out = wmlpT; R = 4096; C = 1024; bx = j & 31; by = j >> 5;
    } else {                    // w2: R=2048 C=1024
        int j = id - 11264; in = w2; out = w2T; R = 2048; C = 1024; bx = j & 31; by = j >> 5;
    }
    int tx = threadIdx.x, ty = threadIdx.y;   // (32,8)
    #pragma unroll
    for (int i = 0; i < 4; i++) {
        int r = by * 32 + ty + i * 8;
        int c = bx * 32 + tx;
        tile[ty + i * 8][tx] = in[(size_t)r * C + c];
    }
    __syncthreads();
    #pragma unroll
    for (int i = 0; i < 4; i++) {
        int ro = bx * 32 + ty + i * 8;   // original col
        int co = by * 32 + tx;           // original row
        out[(size_t)ro * R + co] = f2b(tile[tx][ty + i * 8]);
    }
}

// ---------------- mod = silu(vec) @ w_mod + b_mod (fp32) ----------------
__global__ void k_mod(const float* __restrict__ vec,
                      const float* __restrict__ w_mod,
                      const float* __restrict__ b_mod,
                      float* __restrict__ mod) {
    __shared__ float sv[HID];
    __shared__ float red[8][32];
    int b = blockIdx.y, t = threadIdx.x;
    for (int j = t; j < HID; j += 256) {
        float v = vec[b * HID + j];
        sv[j] = v / (1.0f + __expf(-v));
    }
    __syncthreads();
    int n0 = blockIdx.x * 32;
    int on = t & 31, ks = t >> 5;
    float acc = 0.f;
    const float* wp = w_mod + (size_t)(ks * 128) * 3072 + n0 + on;
    #pragma unroll 4
    for (int k = 0; k < 128; k++) acc += sv[ks * 128 + k] * wp[(size_t)k * 3072];
    red[ks][on] = acc;
    __syncthreads();
    if (t < 32) {
        float s = 0.f;
        #pragma unroll
        for (int i = 0; i < 8; i++) s += red[i][t];
        mod[b * 3072 + n0 + t] = s + b_mod[n0 + t];
    }
}

// ---------------- x_mod = (1+scale)*layernorm(x) + shift, bf16 out ----------------
__global__ void k_lnmod(const float* __restrict__ x,
                        const float* __restrict__ mod,
                        unsigned short* __restrict__ xmod) {
    int tok = blockIdx.x;
    int t = threadIdx.x;
    int b = tok >> 11;
    float4 v4 = *(const float4*)(x + (size_t)tok * HID + t * 4);
    float v0 = v4.x, v1 = v4.y, v2 = v4.z, v3 = v4.w;
    float s  = v0 + v1 + v2 + v3;
    float sq = v0*v0 + v1*v1 + v2*v2 + v3*v3;
    for (int off = 1; off < 64; off <<= 1) {
        s  += __shfl_xor(s,  off);
        sq += __shfl_xor(sq, off);
    }
    __shared__ float ls[4], lq[4];
    int w = t >> 6;
    if ((t & 63) == 0) { ls[w] = s; lq[w] = sq; }
    __syncthreads();
    s  = ls[0] + ls[1] + ls[2] + ls[3];
    sq = lq[0] + lq[1] + lq[2] + lq[3];
    float mean = s * (1.0f / HID);
    float var  = sq * (1.0f / HID) - mean * mean;
    float rstd = rsqrtf(var + 1e-6f);
    const float* mb = mod + b * 3072;
    float y[4] = {v0, v1, v2, v3};
    unsigned short r[4];
    #pragma unroll
    for (int j = 0; j < 4; j++) {
        int col = t * 4 + j;
        float nval = (y[j] - mean) * rstd;
        r[j] = f2b((1.0f + mb[1024 + col]) * nval + mb[col]);
    }
    unsigned int o0 = (unsigned int)r[0] | ((unsigned int)r[1] << 16);
    unsigned int o1 = (unsigned int)r[2] | ((unsigned int)r[3] << 16);
    *(uint2*)(xmod + (size_t)tok * HID + t * 4) = make_uint2(o0, o1);
}

// ---------------- MFMA GEMM (BK=64, global_load_lds staging, XOR-8 swizzle) ----------------
// C[M,N] = A[M,K](bf16) @ Bt[N,K](bf16)^T + bias(f32)
// EPI: 0 = store bf16; 3 = split-K fp32 partial (no bias), gridDim.z splits K
template<int EPI>
__global__ __launch_bounds__(256) void k_gemm(
    const unsigned short* __restrict__ A, int lda,
    const unsigned short* __restrict__ Bt, int ldb,
    const float* __restrict__ bias,
    unsigned short* __restrict__ C, float* __restrict__ Cf, int ldc,
    int K,
    const float* __restrict__ xin,
    const float* __restrict__ mod) {
    __shared__ alignas(16) unsigned short As[128 * 64];
    __shared__ alignas(16) unsigned short Bs[128 * 64];
    int t = threadIdx.x;
    int bm = blockIdx.x, bn = blockIdx.y;
    int lane = t & 63, wave = t >> 6;
    int wm = (wave >> 1) * 64, wn = (wave & 1) * 64;
    int ln = lane & 15, kq = lane >> 4;
    int ln7 = ln & 7;

    f32x4 acc[4][4];
    #pragma unroll
    for (int i = 0; i < 4; i++)
        #pragma unroll
        for (int j = 0; j < 4; j++) acc[i][j] = {0.f, 0.f, 0.f, 0.f};

    int sr  = t >> 3;
    int scg = (t & 7) ^ (sr & 7);
    const unsigned short* Ab = A  + (size_t)(bm * 128) * lda;
    const unsigned short* Bb = Bt + (size_t)(bn * 128) * ldb;

    int ksplit = K / gridDim.z;
    int kbeg = blockIdx.z * ksplit, kend = kbeg + ksplit;

    for (int k0 = kbeg; k0 < kend; k0 += 64) {
        __syncthreads();
        #pragma unroll
        for (int c = 0; c < 4; c++) {
            gl_lds16(Ab + (size_t)(c * 32 + sr) * lda + k0 + scg * 8, &As[c * 2048 + t * 8]);
            gl_lds16(Bb + (size_t)(c * 32 + sr) * ldb + k0 + scg * 8, &Bs[c * 2048 + t * 8]);
        }
        __syncthreads();
        #pragma unroll
        for (int ks = 0; ks < 2; ks++) {
            int slot = ((ks * 4 + kq) ^ ln7) * 8;
            bf16x8 af[4], bfr[4];
            #pragma unroll
            for (int i = 0; i < 4; i++)
                af[i] = *(const bf16x8*)(&As[(wm + i * 16 + ln) * 64 + slot]);
            #pragma unroll
            for (int j = 0; j < 4; j++)
                bfr[j] = *(const bf16x8*)(&Bs[(wn + j * 16 + ln) * 64 + slot]);
            #pragma unroll
            for (int i = 0; i < 4; i++)
                #pragma unroll
                for (int j = 0; j < 4; j++)
                    acc[i][j] = __builtin_amdgcn_mfma_f32_16x16x32_bf16(af[i], bfr[j], acc[i][j], 0, 0, 0);
        }
    }

    #pragma unroll
    for (int i = 0; i < 4; i++) {
        #pragma unroll
        for (int j = 0; j < 4; j++) {
            int col = bn * 128 + wn + j * 16 + ln;
            float bv = (EPI == 3) ? 0.f : bias[col];
            #pragma unroll
            for (int r = 0; r < 4; r++) {
                int row = bm * 128 + wm + i * 16 + kq * 4 + r;
                float v = acc[i][j][r] + bv;
                if (EPI == 0) {
                    C[(size_t)row * ldc + col] = f2b(v);
                } else if (EPI == 1) {
                    C[(size_t)row * ldc + col] = f2b(tanhf(v));
                } else if (EPI == 2) {
                    int b = row >> 11;
                    Cf[(size_t)row * ldc + col] =
                        xin[(size_t)row * HID + col] + mod[b * 3072 + 2048 + col] * v;
                } else {
                    Cf[((size_t)blockIdx.z * TOK + row) * ldc + col] = v;
                }
            }
        }
    }
}

// ---------------- split-K reduce 1: cat[:,1024:] = tanh(p0+p1+bias) ----------------
__global__ __launch_bounds__(256) void k_red1(const float* __restrict__ part,
                                              const float* __restrict__ bias,
                                              unsigned short* __restrict__ cat) {
    int idx = blockIdx.x * 256 + threadIdx.x;
    int row = idx >> 8;
    int c4  = (idx & 255) * 4;
    float4 p0 = *(const float4*)(part + (size_t)row * HID + c4);
    float4 p1 = *(const float4*)(part + ((size_t)TOK + row) * HID + c4);
    float4 bv = *(const float4*)(bias + c4);
    float a0 = tanhf(p0.x + p1.x + bv.x);
    float a1 = tanhf(p0.y + p1.y + bv.y);
    float a2 = tanhf(p0.z + p1.z + bv.z);
    float a3 = tanhf(p0.w + p1.w + bv.w);
    *(uint2*)(&cat[(size_t)row * DCAT + HID + c4]) =
        make_uint2(pkbf2(a0, a1), pkbf2(a2, a3));
}

// ---------------- split-K reduce 2: out = x + gate*(p0+p1+bias) (fp32) ----------------
__global__ __launch_bounds__(256) void k_red2(const float* __restrict__ part,
                                              const float* __restrict__ bias,
                                              const float* __restrict__ x,
                                              const float* __restrict__ mod,
                                              float* __restrict__ out) {
    int idx = blockIdx.x * 256 + threadIdx.x;
    int row = idx >> 8;
    int c4  = (idx & 255) * 4;
    int b = row >> 11;
    float4 p0 = *(const float4*)(part + (size_t)row * HID + c4);
    float4 p1 = *(const float4*)(part + ((size_t)TOK + row) * HID + c4);
    float4 bv = *(const float4*)(bias + c4);
    float4 gv = *(const float4*)(mod + b * 3072 + 2048 + c4);
    float4 xv = *(const float4*)(x + (size_t)row * HID + c4);
    float4 o;
    o.x = xv.x + gv.x * (p0.x + p1.x + bv.x);
    o.y = xv.y + gv.y * (p0.y + p1.y + bv.y);
    o.z = xv.z + gv.z * (p0.z + p1.z + bv.z);
    o.w = xv.w + gv.w * (p0.w + p1.w + bv.w);
    *(float4*)(out + (size_t)row * HID + c4) = o;
}

// ---------------- per-head RMSNorm + RoPE on q,k (in place in h, bf16) ----------------
// q additionally pre-scaled by 0.125*log2(e) so attention softmax runs in exp2 domain.
__global__ void k_qkrope(unsigned short* __restrict__ h,
                         const float* __restrict__ pe,
                         const float* __restrict__ q_scale,
                         const float* __restrict__ k_scale) {
    int tok = blockIdx.x;
    int l = tok & (LL - 1);
    int t = threadIdx.x;
    int lane = t & 63, wave = t >> 6;
    int hh = wave * 4 + (lane >> 4);      // head 0..15
    int d0 = (lane & 15) * 4;             // 4 dims = 2 rope pairs
    unsigned short* row = h + (size_t)tok * D1;
    int i0 = d0 >> 1;
    const float* peb = pe + ((size_t)l * 32 + i0) * 4;
    float4 e0 = *(const float4*)(peb);
    float4 e1 = *(const float4*)(peb + 4);
    #pragma unroll
    for (int qk = 0; qk < 2; qk++) {
        unsigned short* p = row + qk * HID + hh * HD + d0;
        const float* sc = (qk == 0 ? q_scale : k_scale) + d0;
        uint2 qv = *(const uint2*)p;
        float v0 = b2f((unsigned short)(qv.x & 0xFFFF)), v1 = b2f((unsigned short)(qv.x >> 16));
        float v2 = b2f((unsigned short)(qv.y & 0xFFFF)), v3 = b2f((unsigned short)(qv.y >> 16));
        float ssq = v0*v0 + v1*v1 + v2*v2 + v3*v3;
        ssq += __shfl_xor(ssq, 1, 16);
        ssq += __shfl_xor(ssq, 2, 16);
        ssq += __shfl_xor(ssq, 4, 16);
        ssq += __shfl_xor(ssq, 8, 16);
        float rr = rsqrtf(ssq * (1.0f / HD) + 1e-6f);
        if (qk == 0) rr *= 0.18033688011112042f;   // 0.125 * log2(e)
        v0 *= rr * sc[0];
        v1 *= rr * sc[1];
        v2 *= rr * sc[2];
        v3 *= rr * sc[3];
        float o0 = e0.x*v0 + e0.y*v1;
        float o1 = e0.z*v0 + e0.w*v1;
        float o2 = e1.x*v2 + e1.y*v3;
        float o3 = e1.z*v2 + e1.w*v3;
        *(uint2*)p = make_uint2(pkbf2(o0, o1), pkbf2(o2, o3));
    }
}

// ---------------- MFMA flash attention (exp2 domain, 128 Q-rows/block, 8 waves) ----------------
// LDS layout: [row][64] bf16, 128 B rows, XOR-chunk swizzle (T2):
//   physical 16B chunk = logical_chunk ^ (row & 7); reads use (ks*4+quad)^(ln&7).
// QBLK=128: one K/V staging feeds 8 waves (2x MFMA per staged byte vs QBLK=64),
// halves total K/V re-reads. Staging split across 512 threads reusing the
// verified R6 index algebra (K: row/chunk; V: key-pair x 4d inline transpose).
// T14 async-stage: next K/V tile loaded to regs right after LDS writes.
#define KT 64            // keys per tile
__global__ __launch_bounds__(512, 4) void k_attn(const unsigned short* __restrict__ h,
                                                 unsigned short* __restrict__ cat) {
    __shared__ unsigned short Ks[KT * 64];         // [key][d]   swizzled
    __shared__ unsigned short Vt[HD * 64];         // [d][key]   swizzled
    __shared__ unsigned short Ps[8 * 16 * 64];     // per-wave [q][key] swizzled
    int t = threadIdx.x;
    int bx = blockIdx.x;               // Q tile 0..15 (128 rows)
    int bh = blockIdx.y;               // 0..31
    int b = bh >> 4, hh = bh & 15;
    int lane = t & 63, w = t >> 6;     // wave 0..7
    int ln = lane & 15, quad = lane >> 4;
    int ln7 = ln & 7;
    const unsigned short* hb = h + (size_t)b * LL * D1;

    int swk[2];
    swk[0] = ((0 + quad) ^ ln7) * 8;
    swk[1] = ((4 + quad) ^ ln7) * 8;

    bf16x8 qf[2];
    {
        const unsigned short* qbase = hb + (size_t)(bx * 128 + w * 16) * D1 + hh * HD;
        #pragma unroll
        for (int ks = 0; ks < 2; ks++)
            qf[ks] = *(const bf16x8*)(qbase + (size_t)ln * D1 + ks * 32 + quad * 8);
    }

    f32x4 O[4];
    #pragma unroll
    for (int vn = 0; vn < 4; vn++) O[vn] = {0.f, 0.f, 0.f, 0.f};
    float m_ = -1e30f, l_ = 0.f;

    unsigned short* Psw = Ps + w * 16 * 64;

    // staging assignment (512 threads):
    //   K: row = t>>3 (0..63), chunk = t&7  -> 1 u32x4 per thread
    //   V: key pair kp2 = (t&31)*2, d0 = (t>>5)*4 -> 2x uint2 load, 4 u32 stores
    int krow = t >> 3, kc = t & 7;
    int kp2 = (t & 31) * 2, d0 = (t >> 5) * 4;
    const unsigned short* kbase0 = hb + HID + hh * HD;
    const unsigned short* vbase0 = hb + 2 * HID + hh * HD;

    // T14: preload tile 0 into registers
    u32x4 ka = *(const u32x4*)(kbase0 + (size_t)krow * D1 + kc * 8);
    uint2  va = *(const uint2*)(vbase0 + (size_t)kp2 * D1 + d0);
    uint2  vb = *(const uint2*)(vbase0 + (size_t)(kp2 + 1) * D1 + d0);

    for (int kb = 0; kb < LL / KT; kb++) {
        __syncthreads();   // previous tile's LDS reads complete
        {   // write staged regs -> LDS
            *(u32x4*)(&Ks[krow * 64 + ((kc ^ (krow & 7)) * 8)]) = ka;
            #pragma unroll
            for (int j = 0; j < 4; j++) {
                unsigned int aw = (j < 2) ? va.x : va.y;
                unsigned int bw = (j < 2) ? vb.x : vb.y;
                unsigned int lo = (j & 1) ? (aw >> 16) : (aw & 0xFFFFu);
                unsigned int hi = (j & 1) ? (bw >> 16) : (bw & 0xFFFFu);
                int d = d0 + j;
                *(unsigned int*)(&Vt[d * 64 + (kp2 ^ ((d & 7) << 3))]) = lo | (hi << 16);
            }
        }
        __syncthreads();
        if (kb + 1 < LL / KT) {   // T14: issue next-tile loads under compute
            const unsigned short* kb1 = kbase0 + (size_t)(kb + 1) * KT * D1;
            const unsigned short* vb1 = vbase0 + (size_t)(kb + 1) * KT * D1;
            ka = *(const u32x4*)(kb1 + (size_t)krow * D1 + kc * 8);
            va = *(const uint2*)(vb1 + (size_t)kp2 * D1 + d0);
            vb = *(const uint2*)(vb1 + (size_t)(kp2 + 1) * D1 + d0);
        }

        // S^T = K @ Q^T : D[row=key=kt*16+quad*4+r][col=q=ln]
        f32x4 st[4];
        __builtin_amdgcn_s_setprio(1);
        #pragma unroll
        for (int kt = 0; kt < 4; kt++) {
            st[kt] = {0.f, 0.f, 0.f, 0.f};
            #pragma unroll
            for (int ks = 0; ks < 2; ks++) {
                bf16x8 kf = *(const bf16x8*)(&Ks[(kt * 16 + ln) * 64 + swk[ks]]);
                st[kt] = __builtin_amdgcn_mfma_f32_16x16x32_bf16(kf, qf[ks], st[kt], 0, 0, 0);
            }
        }
        __builtin_amdgcn_s_setprio(0);

        // online softmax (exp2 domain, defer-max)
        {
            float p[16];
            #pragma unroll
            for (int kt = 0; kt < 4; kt++)
                #pragma unroll
                for (int r = 0; r < 4; r++) p[kt * 4 + r] = st[kt][r];
            float a0 = fmaxf(fmaxf(p[0],  p[1]),  p[2]);
            float a1 = fmaxf(fmaxf(p[3],  p[4]),  p[5]);
            float a2 = fmaxf(fmaxf(p[6],  p[7]),  p[8]);
            float a3 = fmaxf(fmaxf(p[9],  p[10]), p[11]);
            float a4 = fmaxf(fmaxf(p[12], p[13]), p[14]);
            float mx = fmaxf(fmaxf(fmaxf(a0, a1), a2), fmaxf(fmaxf(a3, a4), p[15]));
            mx = fmaxf(mx, __shfl_xor(mx, 16));
            mx = fmaxf(mx, __shfl_xor(mx, 32));
            if (!__all(mx - m_ <= 10.f)) {
                float mnew = fmaxf(m_, mx);
                float alpha = __builtin_amdgcn_exp2f(m_ - mnew);
                m_ = mnew;
                l_ *= alpha;
                #pragma unroll
                for (int vn = 0; vn < 4; vn++)
                    #pragma unroll
                    for (int r = 0; r < 4; r++) O[vn][r] *= alpha;
            }
            #pragma unroll
            for (int i = 0; i < 16; i++) p[i] = __builtin_amdgcn_exp2f(p[i] - m_);
            float s0 = (p[0] + p[1]) + (p[2] + p[3]);
            float s1 = (p[4] + p[5]) + (p[6] + p[7]);
            float s2 = (p[8] + p[9]) + (p[10] + p[11]);
            float s3 = (p[12] + p[13]) + (p[14] + p[15]);
            float sum = (s0 + s1) + (s2 + s3);
            sum += __shfl_xor(sum, 16);
            sum += __shfl_xor(sum, 32);
            l_ += sum;
            #pragma unroll
            for (int kt = 0; kt < 4; kt++) {
                unsigned int w0 = cvtpk(p[kt*4+0], p[kt*4+1]);
                unsigned int w1 = cvtpk(p[kt*4+2], p[kt*4+3]);
                int pchunk = (2 * kt + (quad >> 1)) ^ ln7;
                *(uint2*)(&Psw[ln * 64 + pchunk * 8 + (quad & 1) * 4]) = make_uint2(w0, w1);
            }
        }

        // O^T += V^T @ P^T
        __builtin_amdgcn_s_setprio(1);
        #pragma unroll
        for (int kt2 = 0; kt2 < 2; kt2++) {
            bf16x8 pb = *(const bf16x8*)(&Psw[ln * 64 + swk[kt2]]);
            #pragma unroll
            for (int vn = 0; vn < 4; vn++) {
                bf16x8 vf = *(const bf16x8*)(&Vt[(vn * 16 + ln) * 64 + swk[kt2]]);
                O[vn] = __builtin_amdgcn_mfma_f32_16x16x32_bf16(vf, pb, O[vn], 0, 0, 0);
            }
        }
        __builtin_amdgcn_s_setprio(0);
    }

    // epilogue: O^T[d][q] / l -> cat[token][hh*64+d]
    {
        float rl = 1.0f / l_;
        size_t row = (size_t)(b * LL + bx * 128 + w * 16 + ln);
        #pragma unroll
        for (int vn = 0; vn < 4; vn++) {
            #pragma unroll
            for (int r2 = 0; r2 < 4; r2 += 2) {
                unsigned int pk = cvtpk(O[vn][r2] * rl, O[vn][r2 + 1] * rl);
                *(unsigned int*)(&cat[row * DCAT + hh * HD + vn * 16 + quad * 4 + r2]) = pk;
            }
        }
    }
}

// ---------------- host launch ----------------
extern "C" void kernel_launch(void* const* d_in, const int* in_sizes, int n_in,
                              void* d_out, int out_size, void* d_ws, size_t ws_size,
                              hipStream_t stream) {
    const float* x       = (const float*)d_in[0];
    const float* vec     = (const float*)d_in[1];
    const float* pe      = (const float*)d_in[2];
    const float* w_mod   = (const float*)d_in[3];
    const float* b_mod   = (const float*)d_in[4];
    const float* w1      = (const float*)d_in[5];
    const float* b1      = (const float*)d_in[6];
    const float* w_mlp   = (const float*)d_in[7];
    const float* b_mlp   = (const float*)d_in[8];
    const float* w2      = (const float*)d_in[9];
    const float* b2      = (const float*)d_in[10];
    const float* q_scale = (const float*)d_in[11];
    const float* k_scale = (const float*)d_in[12];
    float* out = (float*)d_out;

    char* ws = (char*)d_ws;
    size_t off = 0;
    float* mod = (float*)(ws + off);                     off += 6144 * 4;
    unsigned short* xmod  = (unsigned short*)(ws + off); off += (size_t)TOK * HID * 2;
    unsigned short* h     = (unsigned short*)(ws + off); off += (size_t)TOK * D1 * 2;
    unsigned short* cat   = (unsigned short*)(ws + off); off += (size_t)TOK * DCAT * 2;
    unsigned short* w1T   = (unsigned short*)(ws + off); off += (size_t)D1 * HID * 2;
    unsigned short* wmlpT = (unsigned short*)(ws + off); off += (size_t)HID * MLP * 2;
    unsigned short* w2T   = (unsigned short*)(ws + off); off += (size_t)HID * DCAT * 2;
    float* part = (float*)(ws + off);                    off += (size_t)2 * TOK * HID * 4;

    // all 3 weight transposes in one dispatch
    k_transpose3<<<dim3(13312), dim3(32, 8), 0, stream>>>(w1, w1T, w_mlp, wmlpT, w2, w2T);

    k_mod<<<dim3(96, BB), 256, 0, stream>>>(vec, w_mod, b_mod, mod);
    k_lnmod<<<TOK, 256, 0, stream>>>(x, mod, xmod);

    // h = x_mod @ w1 + b1   (M=4096, N=7168, K=1024) — proven 128² kernel
    k_gemm<0><<<dim3(TOK / 128, D1 / 128), 256, 0, stream>>>(
        xmod, HID, w1T, HID, b1, h, nullptr, D1, HID, nullptr, nullptr);

    k_qkrope<<<TOK, 256, 0, stream>>>(h, pe, q_scale, k_scale);

    k_attn<<<dim3(LL / 128, BB * NH), 512, 0, stream>>>(h, cat);

    // mlp partials: h_mlp @ w_mlp   (M=4096, N=1024, K=4096, split-K=2)
    k_gemm<3><<<dim3(TOK / 128, HID / 128, 2), 256, 0, stream>>>(
        h + DQKV, D1, wmlpT, MLP, b_mlp, nullptr, part, HID, MLP, nullptr, nullptr);
    k_red1<<<TOK * HID / 1024, 256, 0, stream>>>(part, b_mlp, cat);

    // out partials: cat @ w2   (M=4096, N=1024, K=2048, split-K=2)
    k_gemm<3><<<dim3(TOK / 128, HID / 128, 2), 256, 0, stream>>>(
        cat, DCAT, w2T, DCAT, b2, nullptr, part, HID, DCAT, nullptr, nullptr);
    k_red2<<<TOK * HID / 1024, 256, 0, stream>>>(part, b2, x, mod, out);
}

// Round 9
// 390.852 us; speedup vs baseline: 1.0381x; 1.0062x over previous
//
#include <hip/hip_runtime.h>
#include <stdint.h>

// SingleStreamBlock on MI355X. fp32 in/out (per reference), bf16 MFMA compute.
// B=2 L=2048 HID=1024 NH=16 HD=64 MLP=4096.

#define HID  1024
#define NH   16
#define HD   64
#define MLP  4096
#define D1   7168   // 3*HID + MLP
#define DQKV 3072
#define DCAT 2048
#define BB   2
#define LL   2048
#define TOK  4096

typedef __attribute__((ext_vector_type(8))) short    bf16x8;
typedef __attribute__((ext_vector_type(4))) float    f32x4;
typedef __attribute__((ext_vector_type(4))) unsigned int u32x4;

__device__ __forceinline__ float b2f(unsigned short u) {
    unsigned int v = ((unsigned int)u) << 16;
    float f; __builtin_memcpy(&f, &v, 4); return f;
}
__device__ __forceinline__ unsigned short f2b(float f) {   // RNE
    unsigned int v; __builtin_memcpy(&v, &f, 4);
    unsigned int r = (v + 0x7FFFu + ((v >> 16) & 1u)) >> 16;
    return (unsigned short)r;
}
// cheap round-to-nearest pack of 2 floats -> 2 bf16 in a u32
__device__ __forceinline__ unsigned int pkbf2(float a, float b) {
    unsigned int ua, ub;
    __builtin_memcpy(&ua, &a, 4); __builtin_memcpy(&ub, &b, 4);
    return ((ua + 0x8000u) >> 16) | ((ub + 0x8000u) & 0xFFFF0000u);
}
// single-instruction pack of 2 f32 -> 2 bf16 (RNE), T12 recipe (no builtin)
__device__ __forceinline__ unsigned int cvtpk(float a, float b) {
    unsigned int r;
    asm("v_cvt_pk_bf16_f32 %0, %1, %2" : "=v"(r) : "v"(a), "v"(b));
    return r;
}
// async global->LDS, 16 B per lane (dest is wave-uniform base + lane*16)
__device__ __forceinline__ void gl_lds16(const unsigned short* g, unsigned short* l) {
    __builtin_amdgcn_global_load_lds(
        (const __attribute__((address_space(1))) unsigned int*)(g),
        (__attribute__((address_space(3))) unsigned int*)(l), 16, 0, 0);
}

// ---------------- merged transpose+cast: fp32 (R x C) -> bf16 (C x R) ----------------
__global__ void k_transpose3(const float* __restrict__ w1, unsigned short* __restrict__ w1T,
                             const float* __restrict__ wmlp, unsigned short* __restrict__ wmlpT,
                             const float* __restrict__ w2, unsigned short* __restrict__ w2T) {
    __shared__ float tile[32][33];
    int id = blockIdx.x;
    const float* in; unsigned short* out; int R, C, bx, by;
    if (id < 7168) {            // w1: R=1024 C=7168
        in = w1; out = w1T; R = 1024; C = 7168; bx = id % 224; by = id / 224;
    } else if (id < 11264) {    // w_mlp: R=4096 C=1024
        int j = id - 7168; in = wmlp; out = wmlpT; R = 4096; C = 1024; bx = j & 31; by = j >> 5;
    } else {                    // w2: R=2048 C=1024
        int j = id - 11264; in = w2; out = w2T; R = 2048; C = 1024; bx = j & 31; by = j >> 5;
    }
    int tx = threadIdx.x, ty = threadIdx.y;   // (32,8)
    #pragma unroll
    for (int i = 0; i < 4; i++) {
        int r = by * 32 + ty + i * 8;
        int c = bx * 32 + tx;
        tile[ty + i * 8][tx] = in[(size_t)r * C + c];
    }
    __syncthreads();
    #pragma unroll
    for (int i = 0; i < 4; i++) {
        int ro = bx * 32 + ty + i * 8;   // original col
        int co = by * 32 + tx;           // original row
        out[(size_t)ro * R + co] = f2b(tile[tx][ty + i * 8]);
    }
}

// ---------------- mod = silu(vec) @ w_mod + b_mod (fp32) ----------------
__global__ void k_mod(const float* __restrict__ vec,
                      const float* __restrict__ w_mod,
                      const float* __restrict__ b_mod,
                      float* __restrict__ mod) {
    __shared__ float sv[HID];
    __shared__ float red[8][32];
    int b = blockIdx.y, t = threadIdx.x;
    for (int j = t; j < HID; j += 256) {
        float v = vec[b * HID + j];
        sv[j] = v / (1.0f + __expf(-v));
    }
    __syncthreads();
    int n0 = blockIdx.x * 32;
    int on = t & 31, ks = t >> 5;
    float acc = 0.f;
    const float* wp = w_mod + (size_t)(ks * 128) * 3072 + n0 + on;
    #pragma unroll 4
    for (int k = 0; k < 128; k++) acc += sv[ks * 128 + k] * wp[(size_t)k * 3072];
    red[ks][on] = acc;
    __syncthreads();
    if (t < 32) {
        float s = 0.f;
        #pragma unroll
        for (int i = 0; i < 8; i++) s += red[i][t];
        mod[b * 3072 + n0 + t] = s + b_mod[n0 + t];
    }
}

// ---------------- x_mod = (1+scale)*layernorm(x) + shift, bf16 out ----------------
__global__ void k_lnmod(const float* __restrict__ x,
                        const float* __restrict__ mod,
                        unsigned short* __restrict__ xmod) {
    int tok = blockIdx.x;
    int t = threadIdx.x;
    int b = tok >> 11;
    float4 v4 = *(const float4*)(x + (size_t)tok * HID + t * 4);
    float v0 = v4.x, v1 = v4.y, v2 = v4.z, v3 = v4.w;
    float s  = v0 + v1 + v2 + v3;
    float sq = v0*v0 + v1*v1 + v2*v2 + v3*v3;
    for (int off = 1; off < 64; off <<= 1) {
        s  += __shfl_xor(s,  off);
        sq += __shfl_xor(sq, off);
    }
    __shared__ float ls[4], lq[4];
    int w = t >> 6;
    if ((t & 63) == 0) { ls[w] = s; lq[w] = sq; }
    __syncthreads();
    s  = ls[0] + ls[1] + ls[2] + ls[3];
    sq = lq[0] + lq[1] + lq[2] + lq[3];
    float mean = s * (1.0f / HID);
    float var  = sq * (1.0f / HID) - mean * mean;
    float rstd = rsqrtf(var + 1e-6f);
    const float* mb = mod + b * 3072;
    float y[4] = {v0, v1, v2, v3};
    unsigned short r[4];
    #pragma unroll
    for (int j = 0; j < 4; j++) {
        int col = t * 4 + j;
        float nval = (y[j] - mean) * rstd;
        r[j] = f2b((1.0f + mb[1024 + col]) * nval + mb[col]);
    }
    unsigned int o0 = (unsigned int)r[0] | ((unsigned int)r[1] << 16);
    unsigned int o1 = (unsigned int)r[2] | ((unsigned int)r[3] << 16);
    *(uint2*)(xmod + (size_t)tok * HID + t * 4) = make_uint2(o0, o1);
}

// ---------------- MFMA GEMM (BK=64, global_load_lds staging, XOR-8 swizzle) ----------------
// C[M,N] = A[M,K](bf16) @ Bt[N,K](bf16)^T + bias(f32)
// EPI: 0 = store bf16; 3 = split-K fp32 partial (no bias), gridDim.z splits K
// SWZ: 1 = big-GEMM 1D launch (1792 blocks) with XCD-supertile mapping:
//   xcd = wg&7 owns region (bm: (xcd&3)*8 .. +8, bn: (xcd>>2)*28 .. +28),
//   traversed bm-fast -> ~64 co-resident blocks span 8x8 tiles = 4.2 MB (L2-fit).
template<int EPI, int SWZ>
__global__ __launch_bounds__(256) void k_gemm(
    const unsigned short* __restrict__ A, int lda,
    const unsigned short* __restrict__ Bt, int ldb,
    const float* __restrict__ bias,
    unsigned short* __restrict__ C, float* __restrict__ Cf, int ldc,
    int K,
    const float* __restrict__ xin,
    const float* __restrict__ mod) {
    __shared__ alignas(16) unsigned short As[128 * 64];
    __shared__ alignas(16) unsigned short Bs[128 * 64];
    int t = threadIdx.x;
    int bm, bn;
    if (SWZ) {
        int wg = blockIdx.x;           // 0..1791
        int xcd = wg & 7, j = wg >> 3; // j 0..223
        bm = ((xcd & 3) << 3) + (j & 7);          // 0..31
        bn = ((xcd >> 2) * 28) + (j >> 3);        // 0..55
    } else {
        bm = blockIdx.x; bn = blockIdx.y;
    }
    int lane = t & 63, wave = t >> 6;
    int wm = (wave >> 1) * 64, wn = (wave & 1) * 64;
    int ln = lane & 15, kq = lane >> 4;
    int ln7 = ln & 7;

    f32x4 acc[4][4];
    #pragma unroll
    for (int i = 0; i < 4; i++)
        #pragma unroll
        for (int j = 0; j < 4; j++) acc[i][j] = {0.f, 0.f, 0.f, 0.f};

    int sr  = t >> 3;
    int scg = (t & 7) ^ (sr & 7);
    const unsigned short* Ab = A  + (size_t)(bm * 128) * lda;
    const unsigned short* Bb = Bt + (size_t)(bn * 128) * ldb;

    int ksplit = K / gridDim.z;
    int kbeg = blockIdx.z * ksplit, kend = kbeg + ksplit;

    for (int k0 = kbeg; k0 < kend; k0 += 64) {
        __syncthreads();
        #pragma unroll
        for (int c = 0; c < 4; c++) {
            gl_lds16(Ab + (size_t)(c * 32 + sr) * lda + k0 + scg * 8, &As[c * 2048 + t * 8]);
            gl_lds16(Bb + (size_t)(c * 32 + sr) * ldb + k0 + scg * 8, &Bs[c * 2048 + t * 8]);
        }
        __syncthreads();
        #pragma unroll
        for (int ks = 0; ks < 2; ks++) {
            int slot = ((ks * 4 + kq) ^ ln7) * 8;
            bf16x8 af[4], bfr[4];
            #pragma unroll
            for (int i = 0; i < 4; i++)
                af[i] = *(const bf16x8*)(&As[(wm + i * 16 + ln) * 64 + slot]);
            #pragma unroll
            for (int j = 0; j < 4; j++)
                bfr[j] = *(const bf16x8*)(&Bs[(wn + j * 16 + ln) * 64 + slot]);
            #pragma unroll
            for (int i = 0; i < 4; i++)
                #pragma unroll
                for (int j = 0; j < 4; j++)
                    acc[i][j] = __builtin_amdgcn_mfma_f32_16x16x32_bf16(af[i], bfr[j], acc[i][j], 0, 0, 0);
        }
    }

    #pragma unroll
    for (int i = 0; i < 4; i++) {
        #pragma unroll
        for (int j = 0; j < 4; j++) {
            int col = bn * 128 + wn + j * 16 + ln;
            float bv = (EPI == 3) ? 0.f : bias[col];
            #pragma unroll
            for (int r = 0; r < 4; r++) {
                int row = bm * 128 + wm + i * 16 + kq * 4 + r;
                float v = acc[i][j][r] + bv;
                if (EPI == 0) {
                    C[(size_t)row * ldc + col] = f2b(v);
                } else if (EPI == 1) {
                    C[(size_t)row * ldc + col] = f2b(tanhf(v));
                } else if (EPI == 2) {
                    int b = row >> 11;
                    Cf[(size_t)row * ldc + col] =
                        xin[(size_t)row * HID + col] + mod[b * 3072 + 2048 + col] * v;
                } else {
                    Cf[((size_t)blockIdx.z * TOK + row) * ldc + col] = v;
                }
            }
        }
    }
}

// ---------------- split-K reduce 1: cat[:,1024:] = tanh(p0+p1+bias) ----------------
__global__ __launch_bounds__(256) void k_red1(const float* __restrict__ part,
                                              const float* __restrict__ bias,
                                              unsigned short* __restrict__ cat) {
    int idx = blockIdx.x * 256 + threadIdx.x;
    int row = idx >> 8;
    int c4  = (idx & 255) * 4;
    float4 p0 = *(const float4*)(part + (size_t)row * HID + c4);
    float4 p1 = *(const float4*)(part + ((size_t)TOK + row) * HID + c4);
    float4 bv = *(const float4*)(bias + c4);
    float a0 = tanhf(p0.x + p1.x + bv.x);
    float a1 = tanhf(p0.y + p1.y + bv.y);
    float a2 = tanhf(p0.z + p1.z + bv.z);
    float a3 = tanhf(p0.w + p1.w + bv.w);
    *(uint2*)(&cat[(size_t)row * DCAT + HID + c4]) =
        make_uint2(pkbf2(a0, a1), pkbf2(a2, a3));
}

// ---------------- split-K reduce 2: out = x + gate*(p0+p1+bias) (fp32) ----------------
__global__ __launch_bounds__(256) void k_red2(const float* __restrict__ part,
                                              const float* __restrict__ bias,
                                              const float* __restrict__ x,
                                              const float* __restrict__ mod,
                                              float* __restrict__ out) {
    int idx = blockIdx.x * 256 + threadIdx.x;
    int row = idx >> 8;
    int c4  = (idx & 255) * 4;
    int b = row >> 11;
    float4 p0 = *(const float4*)(part + (size_t)row * HID + c4);
    float4 p1 = *(const float4*)(part + ((size_t)TOK + row) * HID + c4);
    float4 bv = *(const float4*)(bias + c4);
    float4 gv = *(const float4*)(mod + b * 3072 + 2048 + c4);
    float4 xv = *(const float4*)(x + (size_t)row * HID + c4);
    float4 o;
    o.x = xv.x + gv.x * (p0.x + p1.x + bv.x);
    o.y = xv.y + gv.y * (p0.y + p1.y + bv.y);
    o.z = xv.z + gv.z * (p0.z + p1.z + bv.z);
    o.w = xv.w + gv.w * (p0.w + p1.w + bv.w);
    *(float4*)(out + (size_t)row * HID + c4) = o;
}

// ---------------- per-head RMSNorm + RoPE on q,k (in place in h, bf16) ----------------
// q additionally pre-scaled by 0.125*log2(e) so attention softmax runs in exp2 domain.
__global__ void k_qkrope(unsigned short* __restrict__ h,
                         const float* __restrict__ pe,
                         const float* __restrict__ q_scale,
                         const float* __restrict__ k_scale) {
    int tok = blockIdx.x;
    int l = tok & (LL - 1);
    int t = threadIdx.x;
    int lane = t & 63, wave = t >> 6;
    int hh = wave * 4 + (lane >> 4);      // head 0..15
    int d0 = (lane & 15) * 4;             // 4 dims = 2 rope pairs
    unsigned short* row = h + (size_t)tok * D1;
    int i0 = d0 >> 1;
    const float* peb = pe + ((size_t)l * 32 + i0) * 4;
    float4 e0 = *(const float4*)(peb);
    float4 e1 = *(const float4*)(peb + 4);
    #pragma unroll
    for (int qk = 0; qk < 2; qk++) {
        unsigned short* p = row + qk * HID + hh * HD + d0;
        const float* sc = (qk == 0 ? q_scale : k_scale) + d0;
        uint2 qv = *(const uint2*)p;
        float v0 = b2f((unsigned short)(qv.x & 0xFFFF)), v1 = b2f((unsigned short)(qv.x >> 16));
        float v2 = b2f((unsigned short)(qv.y & 0xFFFF)), v3 = b2f((unsigned short)(qv.y >> 16));
        float ssq = v0*v0 + v1*v1 + v2*v2 + v3*v3;
        ssq += __shfl_xor(ssq, 1, 16);
        ssq += __shfl_xor(ssq, 2, 16);
        ssq += __shfl_xor(ssq, 4, 16);
        ssq += __shfl_xor(ssq, 8, 16);
        float rr = rsqrtf(ssq * (1.0f / HD) + 1e-6f);
        if (qk == 0) rr *= 0.18033688011112042f;   // 0.125 * log2(e)
        v0 *= rr * sc[0];
        v1 *= rr * sc[1];
        v2 *= rr * sc[2];
        v3 *= rr * sc[3];
        float o0 = e0.x*v0 + e0.y*v1;
        float o1 = e0.z*v0 + e0.w*v1;
        float o2 = e1.x*v2 + e1.y*v3;
        float o3 = e1.z*v2 + e1.w*v3;
        *(uint2*)p = make_uint2(pkbf2(o0, o1), pkbf2(o2, o3));
    }
}

// ---------------- MFMA flash attention (exp2 domain, 128 Q-rows/block, 8 waves) ----------------
// LDS layout: [row][64] bf16, 128 B rows, XOR-chunk swizzle (T2).
// QBLK=128: one K/V staging feeds 8 waves; T14 async-stage for next tile.
// XCD head-group swizzle: 1D launch 512 blocks; XCD x gets heads 4x..4x+3
// (64 blocks = its resident capacity at 2/CU) -> K+V (2 MB) stays L2-resident.
#define KT 64            // keys per tile
__global__ __launch_bounds__(512, 4) void k_attn(const unsigned short* __restrict__ h,
                                                 unsigned short* __restrict__ cat) {
    __shared__ unsigned short Ks[KT * 64];         // [key][d]   swizzled
    __shared__ unsigned short Vt[HD * 64];         // [d][key]   swizzled
    __shared__ unsigned short Ps[8 * 16 * 64];     // per-wave [q][key] swizzled
    int t = threadIdx.x;
    int wg = blockIdx.x;               // 0..511
    int xcd = wg & 7, jj = wg >> 3;    // jj 0..63
    int bh = xcd * 4 + (jj >> 4);      // head-batch 0..31 (4 heads per XCD)
    int bx = jj & 15;                  // Q tile 0..15 (128 rows)
    int b = bh >> 4, hh = bh & 15;
    int lane = t & 63, w = t >> 6;     // wave 0..7
    int ln = lane & 15, quad = lane >> 4;
    int ln7 = ln & 7;
    const unsigned short* hb = h + (size_t)b * LL * D1;

    int swk[2];
    swk[0] = ((0 + quad) ^ ln7) * 8;
    swk[1] = ((4 + quad) ^ ln7) * 8;

    bf16x8 qf[2];
    {
        const unsigned short* qbase = hb + (size_t)(bx * 128 + w * 16) * D1 + hh * HD;
        #pragma unroll
        for (int ks = 0; ks < 2; ks++)
            qf[ks] = *(const bf16x8*)(qbase + (size_t)ln * D1 + ks * 32 + quad * 8);
    }

    f32x4 O[4];
    #pragma unroll
    for (int vn = 0; vn < 4; vn++) O[vn] = {0.f, 0.f, 0.f, 0.f};
    float m_ = -1e30f, l_ = 0.f;

    unsigned short* Psw = Ps + w * 16 * 64;

    // staging assignment (512 threads):
    //   K: row = t>>3 (0..63), chunk = t&7  -> 1 u32x4 per thread
    //   V: key pair kp2 = (t&31)*2, d0 = (t>>5)*4 -> 2x uint2 load, 4 u32 stores
    int krow = t >> 3, kc = t & 7;
    int kp2 = (t & 31) * 2, d0 = (t >> 5) * 4;
    const unsigned short* kbase0 = hb + HID + hh * HD;
    const unsigned short* vbase0 = hb + 2 * HID + hh * HD;

    // T14: preload tile 0 into registers
    u32x4 ka = *(const u32x4*)(kbase0 + (size_t)krow * D1 + kc * 8);
    uint2  va = *(const uint2*)(vbase0 + (size_t)kp2 * D1 + d0);
    uint2  vb = *(const uint2*)(vbase0 + (size_t)(kp2 + 1) * D1 + d0);

    for (int kb = 0; kb < LL / KT; kb++) {
        __syncthreads();   // previous tile's LDS reads complete
        {   // write staged regs -> LDS
            *(u32x4*)(&Ks[krow * 64 + ((kc ^ (krow & 7)) * 8)]) = ka;
            #pragma unroll
            for (int j = 0; j < 4; j++) {
                unsigned int aw = (j < 2) ? va.x : va.y;
                unsigned int bw = (j < 2) ? vb.x : vb.y;
                unsigned int lo = (j & 1) ? (aw >> 16) : (aw & 0xFFFFu);
                unsigned int hi = (j & 1) ? (bw >> 16) : (bw & 0xFFFFu);
                int d = d0 + j;
                *(unsigned int*)(&Vt[d * 64 + (kp2 ^ ((d & 7) << 3))]) = lo | (hi << 16);
            }
        }
        __syncthreads();
        if (kb + 1 < LL / KT) {   // T14: issue next-tile loads under compute
            const unsigned short* kb1 = kbase0 + (size_t)(kb + 1) * KT * D1;
            const unsigned short* vb1 = vbase0 + (size_t)(kb + 1) * KT * D1;
            ka = *(const u32x4*)(kb1 + (size_t)krow * D1 + kc * 8);
            va = *(const uint2*)(vb1 + (size_t)kp2 * D1 + d0);
            vb = *(const uint2*)(vb1 + (size_t)(kp2 + 1) * D1 + d0);
        }

        // S^T = K @ Q^T : D[row=key=kt*16+quad*4+r][col=q=ln]
        f32x4 st[4];
        __builtin_amdgcn_s_setprio(1);
        #pragma unroll
        for (int kt = 0; kt < 4; kt++) {
            st[kt] = {0.f, 0.f, 0.f, 0.f};
            #pragma unroll
            for (int ks = 0; ks < 2; ks++) {
                bf16x8 kf = *(const bf16x8*)(&Ks[(kt * 16 + ln) * 64 + swk[ks]]);
                st[kt] = __builtin_amdgcn_mfma_f32_16x16x32_bf16(kf, qf[ks], st[kt], 0, 0, 0);
            }
        }
        __builtin_amdgcn_s_setprio(0);

        // online softmax (exp2 domain, defer-max)
        {
            float p[16];
            #pragma unroll
            for (int kt = 0; kt < 4; kt++)
                #pragma unroll
                for (int r = 0; r < 4; r++) p[kt * 4 + r] = st[kt][r];
            float a0 = fmaxf(fmaxf(p[0],  p[1]),  p[2]);
            float a1 = fmaxf(fmaxf(p[3],  p[4]),  p[5]);
            float a2 = fmaxf(fmaxf(p[6],  p[7]),  p[8]);
            float a3 = fmaxf(fmaxf(p[9],  p[10]), p[11]);
            float a4 = fmaxf(fmaxf(p[12], p[13]), p[14]);
            float mx = fmaxf(fmaxf(fmaxf(a0, a1), a2), fmaxf(fmaxf(a3, a4), p[15]));
            mx = fmaxf(mx, __shfl_xor(mx, 16));
            mx = fmaxf(mx, __shfl_xor(mx, 32));
            if (!__all(mx - m_ <= 10.f)) {
                float mnew = fmaxf(m_, mx);
                float alpha = __builtin_amdgcn_exp2f(m_ - mnew);
                m_ = mnew;
                l_ *= alpha;
                #pragma unroll
                for (int vn = 0; vn < 4; vn++)
                    #pragma unroll
                    for (int r = 0; r < 4; r++) O[vn][r] *= alpha;
            }
            #pragma unroll
            for (int i = 0; i < 16; i++) p[i] = __builtin_amdgcn_exp2f(p[i] - m_);
            float s0 = (p[0] + p[1]) + (p[2] + p[3]);
            float s1 = (p[4] + p[5]) + (p[6] + p[7]);
            float s2 = (p[8] + p[9]) + (p[10] + p[11]);
            float s3 = (p[12] + p[13]) + (p[14] + p[15]);
            float sum = (s0 + s1) + (s2 + s3);
            sum += __shfl_xor(sum, 16);
            sum += __shfl_xor(sum, 32);
            l_ += sum;
            #pragma unroll
            for (int kt = 0; kt < 4; kt++) {
                unsigned int w0 = cvtpk(p[kt*4+0], p[kt*4+1]);
                unsigned int w1 = cvtpk(p[kt*4+2], p[kt*4+3]);
                int pchunk = (2 * kt + (quad >> 1)) ^ ln7;
                *(uint2*)(&Psw[ln * 64 + pchunk * 8 + (quad & 1) * 4]) = make_uint2(w0, w1);
            }
        }

        // O^T += V^T @ P^T
        __builtin_amdgcn_s_setprio(1);
        #pragma unroll
        for (int kt2 = 0; kt2 < 2; kt2++) {
            bf16x8 pb = *(const bf16x8*)(&Psw[ln * 64 + swk[kt2]]);
            #pragma unroll
            for (int vn = 0; vn < 4; vn++) {
                bf16x8 vf = *(const bf16x8*)(&Vt[(vn * 16 + ln) * 64 + swk[kt2]]);
                O[vn] = __builtin_amdgcn_mfma_f32_16x16x32_bf16(vf, pb, O[vn], 0, 0, 0);
            }
        }
        __builtin_amdgcn_s_setprio(0);
    }

    // epilogue: O^T[d][q] / l -> cat[token][hh*64+d]
    {
        float rl = 1.0f / l_;
        size_t row = (size_t)(b * LL + bx * 128 + w * 16 + ln);
        #pragma unroll
        for (int vn = 0; vn < 4; vn++) {
            #pragma unroll
            for (int r2 = 0; r2 < 4; r2 += 2) {
                unsigned int pk = cvtpk(O[vn][r2] * rl, O[vn][r2 + 1] * rl);
                *(unsigned int*)(&cat[row * DCAT + hh * HD + vn * 16 + quad * 4 + r2]) = pk;
            }
        }
    }
}

// ---------------- host launch ----------------
extern "C" void kernel_launch(void* const* d_in, const int* in_sizes, int n_in,
                              void* d_out, int out_size, void* d_ws, size_t ws_size,
                              hipStream_t stream) {
    const float* x       = (const float*)d_in[0];
    const float* vec     = (const float*)d_in[1];
    const float* pe      = (const float*)d_in[2];
    const float* w_mod   = (const float*)d_in[3];
    const float* b_mod   = (const float*)d_in[4];
    const float* w1      = (const float*)d_in[5];
    const float* b1      = (const float*)d_in[6];
    const float* w_mlp   = (const float*)d_in[7];
    const float* b_mlp   = (const float*)d_in[8];
    const float* w2      = (const float*)d_in[9];
    const float* b2      = (const float*)d_in[10];
    const float* q_scale = (const float*)d_in[11];
    const float* k_scale = (const float*)d_in[12];
    float* out = (float*)d_out;

    char* ws = (char*)d_ws;
    size_t off = 0;
    float* mod = (float*)(ws + off);                     off += 6144 * 4;
    unsigned short* xmod  = (unsigned short*)(ws + off); off += (size_t)TOK * HID * 2;
    unsigned short* h     = (unsigned short*)(ws + off); off += (size_t)TOK * D1 * 2;
    unsigned short* cat   = (unsigned short*)(ws + off); off += (size_t)TOK * DCAT * 2;
    unsigned short* w1T   = (unsigned short*)(ws + off); off += (size_t)D1 * HID * 2;
    unsigned short* wmlpT = (unsigned short*)(ws + off); off += (size_t)HID * MLP * 2;
    unsigned short* w2T   = (unsigned short*)(ws + off); off += (size_t)HID * DCAT * 2;
    float* part = (float*)(ws + off);                    off += (size_t)2 * TOK * HID * 4;

    // all 3 weight transposes in one dispatch
    k_transpose3<<<dim3(13312), dim3(32, 8), 0, stream>>>(w1, w1T, w_mlp, wmlpT, w2, w2T);

    k_mod<<<dim3(96, BB), 256, 0, stream>>>(vec, w_mod, b_mod, mod);
    k_lnmod<<<TOK, 256, 0, stream>>>(x, mod, xmod);

    // h = x_mod @ w1 + b1   (M=4096, N=7168, K=1024) — 128², XCD-supertile swizzle
    k_gemm<0, 1><<<dim3((TOK / 128) * (D1 / 128)), 256, 0, stream>>>(
        xmod, HID, w1T, HID, b1, h, nullptr, D1, HID, nullptr, nullptr);

    k_qkrope<<<TOK, 256, 0, stream>>>(h, pe, q_scale, k_scale);

    k_attn<<<dim3((LL / 128) * BB * NH), 512, 0, stream>>>(h, cat);

    // mlp partials: h_mlp @ w_mlp   (M=4096, N=1024, K=4096, split-K=2)
    k_gemm<3, 0><<<dim3(TOK / 128, HID / 128, 2), 256, 0, stream>>>(
        h + DQKV, D1, wmlpT, MLP, b_mlp, nullptr, part, HID, MLP, nullptr, nullptr);
    k_red1<<<TOK * HID / 1024, 256, 0, stream>>>(part, b_mlp, cat);

    // out partials: cat @ w2   (M=4096, N=1024, K=2048, split-K=2)
    k_gemm<3, 0><<<dim3(TOK / 128, HID / 128, 2), 256, 0, stream>>>(
        cat, DCAT, w2T, DCAT, b2, nullptr, part, HID, DCAT, nullptr, nullptr);
    k_red2<<<TOK * HID / 1024, 256, 0, stream>>>(part, b2, x, mod, out);
}